// Round 9
// baseline (143.608 us; speedup 1.0000x reference)
//
#include <hip/hip_runtime.h>
#include <math.h>

namespace {
constexpr int kB = 4;
constexpr int kS = 4096;
constexpr int kH = 4096;
constexpr int kE = 16;
constexpr int kTokens = kB * kS;            // 16384
constexpr int kHalf = kH / 2;               // 2048 floats per H-half
constexpr int kChunk = 256;                 // floats per j-iter (float4/lane)
constexpr int kNCh = kHalf / kChunk;        // 8 chunks per half
constexpr int kThreads1 = 1024;             // 16 waves
constexpr int kTokBlk = 32;                 // tokens per block (2 per wave)
constexpr int kGrid1 = (kTokens / kTokBlk) * 2;  // 1024 (x2 for H-halves)
constexpr int kThreads2 = 256;
constexpr int kGrid2 = kTokens / kThreads2;      // 64
}  // namespace

__device__ __forceinline__ void gload_lds16(const float* src_lane, float* lds_base) {
  // wave-uniform LDS base; HW adds lane*16. Linear dest + per-lane global src.
  __builtin_amdgcn_global_load_lds(
      (const __attribute__((address_space(1))) void*)src_lane,
      (__attribute__((address_space(3))) void*)lds_base, 16, 0, 0);
}

// Phase 1: partial gate GEMM over one H-half. W-half staged to LDS ONCE (one
// barrier total); x streams HBM->registers read exactly once chip-wide; main
// loop has NO barriers and NO manual waitcnt (compiler schedules). Each wave:
// 2 tokens x 16 experts, 3-slot statically-indexed x prefetch ring.
__global__ __launch_bounds__(kThreads1, 4) void router_partial(
    const float* __restrict__ x, const float* __restrict__ W,
    float* __restrict__ partial) {   // [2][kTokens][kE]
  __shared__ float s_w[kE][kHalf];   // 128 KiB
  const int tid = threadIdx.x;
  const int wave = tid >> 6;         // 0..15 == expert row this wave stages
  const int lane = tid & 63;
  const int h = blockIdx.x & 1;      // H-half
  const int g = blockIdx.x >> 1;     // token group
  const int tokA = g * kTokBlk + wave * 2;

  // Stage this wave's W row-half: 8 x 1KB gload_lds, linear dest.
  {
    const float* src = W + (size_t)wave * kH + h * kHalf + lane * 4;
#pragma unroll
    for (int c = 0; c < kNCh; ++c)
      gload_lds16(src + c * kChunk, &s_w[wave][c * kChunk]);
  }

  float acc[2][kE];
#pragma unroll
  for (int t = 0; t < 2; ++t)
#pragma unroll
    for (int e = 0; e < kE; ++e) acc[t][e] = 0.f;

  const float* xa = x + (size_t)tokA * kH + h * kHalf + lane * 4;
  const float* xb = xa + kH;          // token tokA+1

  __syncthreads();                    // single barrier: W resident (vmcnt drain)

  // 3-slot prefetch ring, fully unrolled so every index is compile-time.
  float4 a0, a1, b0, b1, c0, c1;
  auto LA = [&](int j) { a0 = *reinterpret_cast<const float4*>(xa + j * kChunk);
                         a1 = *reinterpret_cast<const float4*>(xb + j * kChunk); };
  auto LB = [&](int j) { b0 = *reinterpret_cast<const float4*>(xa + j * kChunk);
                         b1 = *reinterpret_cast<const float4*>(xb + j * kChunk); };
  auto LC = [&](int j) { c0 = *reinterpret_cast<const float4*>(xa + j * kChunk);
                         c1 = *reinterpret_cast<const float4*>(xb + j * kChunk); };
  auto CMP = [&](int j, const float4& x0, const float4& x1) {
#pragma unroll
    for (int ep = 0; ep < 4; ++ep) {
      float4 wv[4];
#pragma unroll
      for (int e = 0; e < 4; ++e)
        wv[e] = *reinterpret_cast<const float4*>(
            &s_w[ep * 4 + e][j * kChunk + lane * 4]);
#pragma unroll
      for (int e = 0; e < 4; ++e) {
        const int ei = ep * 4 + e;
        acc[0][ei] = fmaf(x0.x, wv[e].x, acc[0][ei]);
        acc[0][ei] = fmaf(x0.y, wv[e].y, acc[0][ei]);
        acc[0][ei] = fmaf(x0.z, wv[e].z, acc[0][ei]);
        acc[0][ei] = fmaf(x0.w, wv[e].w, acc[0][ei]);
        acc[1][ei] = fmaf(x1.x, wv[e].x, acc[1][ei]);
        acc[1][ei] = fmaf(x1.y, wv[e].y, acc[1][ei]);
        acc[1][ei] = fmaf(x1.z, wv[e].z, acc[1][ei]);
        acc[1][ei] = fmaf(x1.w, wv[e].w, acc[1][ei]);
      }
    }
  };

  LA(0); LB(1);
  LC(2); CMP(0, a0, a1);
  LA(3); CMP(1, b0, b1);
  LB(4); CMP(2, c0, c1);
  LC(5); CMP(3, a0, a1);
  LA(6); CMP(4, b0, b1);
  LB(7); CMP(5, c0, c1);
  CMP(6, a0, a1);
  CMP(7, b0, b1);

  // Butterfly: every lane ends with the full half-H sums for its 2x16 tile.
#pragma unroll
  for (int off = 1; off < 64; off <<= 1) {
#pragma unroll
    for (int t = 0; t < 2; ++t)
#pragma unroll
      for (int e = 0; e < kE; ++e)
        acc[t][e] += __shfl_xor(acc[t][e], off, 64);
  }

  if (lane < 2) {
    float* dst = partial + ((size_t)h * kTokens + tokA + lane) * kE;
#pragma unroll
    for (int e = 0; e < kE; ++e) dst[e] = acc[lane][e];
  }
}

// Phase 2: combine halves, softmax, top-2, outputs, per-block aux partials.
__global__ __launch_bounds__(kThreads2) void router_finish(
    const float* __restrict__ partial, float* __restrict__ out_probs,
    float* __restrict__ out_idx, float* __restrict__ gpart) {
  __shared__ float s_cnt[kE];
  __shared__ float s_psum[kE];
  const int tid = threadIdx.x;
  const int lane = tid & 63;
  const int tok = blockIdx.x * kThreads2 + tid;

  if (tid < kE) { s_cnt[tid] = 0.f; s_psum[tid] = 0.f; }
  __syncthreads();

  float l[kE];
#pragma unroll
  for (int e = 0; e < kE; ++e)
    l[e] = partial[(size_t)tok * kE + e] +
           partial[((size_t)kTokens + tok) * kE + e];

  float m = l[0];
#pragma unroll
  for (int e = 1; e < kE; ++e) m = fmaxf(m, l[e]);
  float p[kE];
  float s = 0.f;
#pragma unroll
  for (int e = 0; e < kE; ++e) { p[e] = __expf(l[e] - m); s += p[e]; }
  const float inv = 1.f / s;
#pragma unroll
  for (int e = 0; e < kE; ++e) p[e] *= inv;

  // top-2 on probs (reference: top_k AFTER softmax; ties -> lowest index)
  int i1 = 0;
  float v1 = p[0];
#pragma unroll
  for (int e = 1; e < kE; ++e)
    if (p[e] > v1) { v1 = p[e]; i1 = e; }
  int i2 = (i1 == 0) ? 1 : 0;
  float v2 = p[i2];
#pragma unroll
  for (int e = 0; e < kE; ++e) {
    if (e == i1) continue;
    if (p[e] > v2) { v2 = p[e]; i2 = e; }
  }

  const float ns = 1.f / (v1 + v2);
  out_probs[tok * 2 + 0] = v1 * ns;
  out_probs[tok * 2 + 1] = v2 * ns;
  out_idx[tok * 2 + 0] = (float)i1;
  out_idx[tok * 2 + 1] = (float)i2;

  // psum: wave-reduce p[e] (shfl butterfly) then one atomic per wave per e.
#pragma unroll
  for (int off = 1; off < 64; off <<= 1)
#pragma unroll
    for (int e = 0; e < kE; ++e) p[e] += __shfl_xor(p[e], off, 64);
  if (lane == 0)
#pragma unroll
    for (int e = 0; e < kE; ++e) atomicAdd(&s_psum[e], p[e]);
  // counts: two LDS atomics per thread (cheap, exact).
  atomicAdd(&s_cnt[i1], 1.f);
  atomicAdd(&s_cnt[i2], 1.f);

  __syncthreads();
  if (tid < 2 * kE)
    gpart[(size_t)blockIdx.x * 2 * kE + tid] =
        (tid < kE) ? s_cnt[tid] : s_psum[tid - kE];
}

// Phase 3: reduce 64 block-partials; aux = E * sum_e (cnt_e/B) * (psum_e/(B*S)).
__global__ __launch_bounds__(1024) void aux_finish(
    const float* __restrict__ gpart, float* __restrict__ out_aux) {
  __shared__ float s_final[2 * kE];
  const int tid = threadIdx.x;
  const int c = tid >> 5;       // 0..31: partial column
  const int k = tid & 31;       // 0..31: row pair index
  float s = gpart[(size_t)k * 32 + c] + gpart[(size_t)(k + 32) * 32 + c];
#pragma unroll
  for (int off = 1; off < 32; off <<= 1) s += __shfl_xor(s, off, 64);
  if (k == 0) s_final[c] = s;
  __syncthreads();
  if (tid == 0) {
    double acc = 0.0;
    for (int e = 0; e < kE; ++e)
      acc += (double)s_final[e] * (double)s_final[kE + e];
    out_aux[0] = (float)(acc * (double)kE / ((double)kB * (double)kB * (double)kS));
  }
}

extern "C" void kernel_launch(void* const* d_in, const int* in_sizes, int n_in,
                              void* d_out, int out_size, void* d_ws, size_t ws_size,
                              hipStream_t stream) {
  const float* x = (const float*)d_in[0];   // [B,S,H] f32
  const float* W = (const float*)d_in[1];   // [E,H]   f32
  float* out = (float*)d_out;               // [32768 probs][32768 idx][1 aux]
  float* partial = (float*)d_ws;            // [2][kTokens][kE] = 2 MiB
  float* gpart = partial + 2 * (size_t)kTokens * kE;  // [kGrid2][32]

  router_partial<<<kGrid1, kThreads1, 0, stream>>>(x, W, partial);
  router_finish<<<kGrid2, kThreads2, 0, stream>>>(
      partial, out, out + 2 * kTokens, gpart);
  aux_finish<<<1, 1024, 0, stream>>>(gpart, out + 4 * kTokens);
}

// Round 10
// 115.643 us; speedup vs baseline: 1.2418x; 1.2418x over previous
//
#include <hip/hip_runtime.h>
#include <math.h>

namespace {
constexpr int kB = 4;
constexpr int kS = 4096;
constexpr int kH = 4096;
constexpr int kE = 16;
constexpr int kTokens = kB * kS;            // 16384
constexpr int kT = 4;                       // tokens per wave (ALL 16 experts)
constexpr int kWaves = 4;
constexpr int kThreads = 64 * kWaves;       // 256
constexpr int kTokBlk = kT * kWaves;        // 16 tokens per block
constexpr int kGrid = kTokens / kTokBlk;    // 1024 = 4 blocks/CU, all resident
constexpr int kChunk = 256;                 // floats of H per j-iter (float4/lane)
constexpr int kNC = kH / kChunk;            // 16
}  // namespace

// Pure-streaming gate GEMM (R5 discipline: no LDS / barriers / manual waitcnt
// in the main loop — the compiler schedules). Tile: 4 tokens x ALL 16 experts
// per wave -> x read exactly once chip-wide. W in 4 sub-phases of 4 rows keeps
// live regs ~100. amdgpu_waves_per_eu(4,4) pins the allocator to a 128-VGPR
// budget so it cannot repeat the R2/R9 voluntary-spill failure.
__global__ __attribute__((amdgpu_waves_per_eu(4, 4)))
__launch_bounds__(kThreads) void router_main(
    const float* __restrict__ x, const float* __restrict__ W,
    float* __restrict__ out_probs,   // [kTokens][2]
    float* __restrict__ out_idx,     // [kTokens][2] (indices as float)
    float* __restrict__ gpart) {     // [kGrid][32]: cnt[16], psum[16] per block
  __shared__ float s_cnt[kE];
  __shared__ float s_psum[kE];

  const int tid = threadIdx.x;
  const int wave = tid >> 6;
  const int lane = tid & 63;
  const int tok0 = blockIdx.x * kTokBlk + wave * kT;

  if (tid < kE) { s_cnt[tid] = 0.f; s_psum[tid] = 0.f; }

  const float* xb = x + (size_t)tok0 * kH + lane * 4;
  const float* wb = W + lane * 4;

  float acc[kT][kE];
#pragma unroll
  for (int t = 0; t < kT; ++t)
#pragma unroll
    for (int e = 0; e < kE; ++e) acc[t][e] = 0.f;

  for (int j = 0; j < kNC; ++j) {
    const size_t off = (size_t)j * kChunk;
    // x: 4 coalesced float4 (the HBM stream), issued up front.
    float4 xv[kT];
#pragma unroll
    for (int t = 0; t < kT; ++t)
      xv[t] = *reinterpret_cast<const float4*>(xb + (size_t)t * kH + off);
    // W: 4 sub-phases x 4 rows (wv reused -> only 16 live regs for W).
#pragma unroll
    for (int p = 0; p < 4; ++p) {
      float4 wv[4];
#pragma unroll
      for (int e = 0; e < 4; ++e)
        wv[e] = *reinterpret_cast<const float4*>(
            wb + (size_t)(p * 4 + e) * kH + off);
#pragma unroll
      for (int e = 0; e < 4; ++e) {
        const int ei = p * 4 + e;
#pragma unroll
        for (int t = 0; t < kT; ++t) {
          acc[t][ei] = fmaf(xv[t].x, wv[e].x, acc[t][ei]);
          acc[t][ei] = fmaf(xv[t].y, wv[e].y, acc[t][ei]);
          acc[t][ei] = fmaf(xv[t].z, wv[e].z, acc[t][ei]);
          acc[t][ei] = fmaf(xv[t].w, wv[e].w, acc[t][ei]);
        }
      }
    }
  }

  // Butterfly: every lane ends with full-H sums for the wave's 4x16 tile.
#pragma unroll
  for (int off = 1; off < 64; off <<= 1) {
#pragma unroll
    for (int t = 0; t < kT; ++t)
#pragma unroll
      for (int e = 0; e < kE; ++e)
        acc[t][e] += __shfl_xor(acc[t][e], off, 64);
  }

  __syncthreads();   // s_cnt/s_psum zeroed before any atomics land

  // Lanes 0..3: one token each — softmax, top-2, outputs, aux partials.
  if (lane < kT) {
    const int tok = tok0 + lane;
    float l[kE];
#pragma unroll
    for (int e = 0; e < kE; ++e) l[e] = acc[lane][e];

    float m = l[0];
#pragma unroll
    for (int e = 1; e < kE; ++e) m = fmaxf(m, l[e]);
    float p[kE];
    float s = 0.f;
#pragma unroll
    for (int e = 0; e < kE; ++e) { p[e] = __expf(l[e] - m); s += p[e]; }
    const float inv = 1.f / s;
#pragma unroll
    for (int e = 0; e < kE; ++e) p[e] *= inv;

    // top-2 on probs (reference: top_k AFTER softmax; ties -> lowest index)
    int i1 = 0;
    float v1 = p[0];
#pragma unroll
    for (int e = 1; e < kE; ++e)
      if (p[e] > v1) { v1 = p[e]; i1 = e; }
    int i2 = (i1 == 0) ? 1 : 0;
    float v2 = p[i2];
#pragma unroll
    for (int e = 0; e < kE; ++e) {
      if (e == i1) continue;
      if (p[e] > v2) { v2 = p[e]; i2 = e; }
    }

    const float ns = 1.f / (v1 + v2);
    out_probs[tok * 2 + 0] = v1 * ns;
    out_probs[tok * 2 + 1] = v2 * ns;
    out_idx[tok * 2 + 0] = (float)i1;
    out_idx[tok * 2 + 1] = (float)i2;

#pragma unroll
    for (int e = 0; e < kE; ++e) atomicAdd(&s_psum[e], p[e]);
    atomicAdd(&s_cnt[i1], 1.f);
    atomicAdd(&s_cnt[i2], 1.f);
  }
  __syncthreads();
  // Per-block partials (coalesced store); reduced by aux_finish.
  if (tid < 2 * kE)
    gpart[(size_t)blockIdx.x * 2 * kE + tid] =
        (tid < kE) ? s_cnt[tid] : s_psum[tid - kE];
}

// Reduce per-block partials; aux = E * sum_e (cnt_e/B) * (psum_e/(B*S)).
__global__ __launch_bounds__(1024) void aux_finish(
    const float* __restrict__ gpart, float* __restrict__ out_aux) {
  __shared__ float s_red[32][32];
  __shared__ float s_final[32];
  const int tid = threadIdx.x;
  const int c = tid & 31;       // column: 0-15 cnt, 16-31 psum
  const int r0 = tid >> 5;      // row-slice 0..31
  float s = 0.f;
  for (int k = 0; k < kGrid / 32; ++k)
    s += gpart[(size_t)(r0 * (kGrid / 32) + k) * 32 + c];
  s_red[r0][c] = s;
  __syncthreads();
  if (tid < 32) {
    float t = 0.f;
    for (int r = 0; r < 32; ++r) t += s_red[r][tid];
    s_final[tid] = t;
  }
  __syncthreads();
  if (tid == 0) {
    double acc = 0.0;
    for (int e = 0; e < kE; ++e)
      acc += (double)s_final[e] * (double)s_final[kE + e];
    out_aux[0] = (float)(acc * (double)kE / ((double)kB * (double)kB * (double)kS));
  }
}

extern "C" void kernel_launch(void* const* d_in, const int* in_sizes, int n_in,
                              void* d_out, int out_size, void* d_ws, size_t ws_size,
                              hipStream_t stream) {
  const float* x = (const float*)d_in[0];   // [B,S,H] f32
  const float* W = (const float*)d_in[1];   // [E,H]   f32
  float* out = (float*)d_out;               // [32768 probs][32768 idx][1 aux]
  float* gpart = (float*)d_ws;              // [kGrid][32], fully overwritten

  router_main<<<kGrid, kThreads, 0, stream>>>(
      x, W, out, out + 2 * kTokens, gpart);
  aux_finish<<<1, 1024, 0, stream>>>(gpart, out + 4 * kTokens);
}